// Round 4
// baseline (199.488 us; speedup 1.0000x reference)
//
#include <hip/hip_runtime.h>

#define R_ 512
#define K_ 250
#define E_ 16
#define L_ 2
#define SX_S 20   // padded s_x row stride (floats) to spread LDS banks

// fold 1/sqrt(D)=0.5 and log2(e) into q so softmax prob = exp2(dot)
#define SCALE_LOG2E 0.72134752044448170f

#define ATT_STEP(KP, VP) do {                                                        \
    const float4 k0 = ((const float4*)(KP))[0];                                      \
    const float4 k1 = ((const float4*)(KP))[1];                                      \
    const float4 k2 = ((const float4*)(KP))[2];                                      \
    const float4 k3 = ((const float4*)(KP))[3];                                      \
    float s00 = fmaf(q0[0],k0.x, fmaf(q0[1],k0.y, fmaf(q0[2],k0.z, q0[3]*k0.w)));    \
    float s01 = fmaf(q0[4],k1.x, fmaf(q0[5],k1.y, fmaf(q0[6],k1.z, q0[7]*k1.w)));    \
    float s02 = fmaf(q0[8],k2.x, fmaf(q0[9],k2.y, fmaf(q0[10],k2.z, q0[11]*k2.w)));  \
    float s03 = fmaf(q0[12],k3.x, fmaf(q0[13],k3.y, fmaf(q0[14],k3.z, q0[15]*k3.w)));\
    float s10 = fmaf(q1[0],k0.x, fmaf(q1[1],k0.y, fmaf(q1[2],k0.z, q1[3]*k0.w)));    \
    float s11 = fmaf(q1[4],k1.x, fmaf(q1[5],k1.y, fmaf(q1[6],k1.z, q1[7]*k1.w)));    \
    float s12 = fmaf(q1[8],k2.x, fmaf(q1[9],k2.y, fmaf(q1[10],k2.z, q1[11]*k2.w)));  \
    float s13 = fmaf(q1[12],k3.x, fmaf(q1[13],k3.y, fmaf(q1[14],k3.z, q1[15]*k3.w)));\
    const float p00 = __builtin_amdgcn_exp2f(s00);                                   \
    const float p01 = __builtin_amdgcn_exp2f(s01);                                   \
    const float p02 = __builtin_amdgcn_exp2f(s02);                                   \
    const float p03 = __builtin_amdgcn_exp2f(s03);                                   \
    const float p10 = __builtin_amdgcn_exp2f(s10);                                   \
    const float p11 = __builtin_amdgcn_exp2f(s11);                                   \
    const float p12 = __builtin_amdgcn_exp2f(s12);                                   \
    const float p13 = __builtin_amdgcn_exp2f(s13);                                   \
    const float4 v0 = ((const float4*)(VP))[0];                                      \
    const float4 v1 = ((const float4*)(VP))[1];                                      \
    const float4 v2 = ((const float4*)(VP))[2];                                      \
    const float4 v3 = ((const float4*)(VP))[3];                                      \
    ls0 += p00; ls1 += p01; ls2 += p02; ls3 += p03;                                  \
    ls4 += p10; ls5 += p11; ls6 += p12; ls7 += p13;                                  \
    acc0[0]  = fmaf(p00, v0.x, acc0[0]);  acc0[1]  = fmaf(p00, v0.y, acc0[1]);       \
    acc0[2]  = fmaf(p00, v0.z, acc0[2]);  acc0[3]  = fmaf(p00, v0.w, acc0[3]);       \
    acc0[4]  = fmaf(p01, v1.x, acc0[4]);  acc0[5]  = fmaf(p01, v1.y, acc0[5]);       \
    acc0[6]  = fmaf(p01, v1.z, acc0[6]);  acc0[7]  = fmaf(p01, v1.w, acc0[7]);       \
    acc0[8]  = fmaf(p02, v2.x, acc0[8]);  acc0[9]  = fmaf(p02, v2.y, acc0[9]);       \
    acc0[10] = fmaf(p02, v2.z, acc0[10]); acc0[11] = fmaf(p02, v2.w, acc0[11]);      \
    acc0[12] = fmaf(p03, v3.x, acc0[12]); acc0[13] = fmaf(p03, v3.y, acc0[13]);      \
    acc0[14] = fmaf(p03, v3.z, acc0[14]); acc0[15] = fmaf(p03, v3.w, acc0[15]);      \
    acc1[0]  = fmaf(p10, v0.x, acc1[0]);  acc1[1]  = fmaf(p10, v0.y, acc1[1]);       \
    acc1[2]  = fmaf(p10, v0.z, acc1[2]);  acc1[3]  = fmaf(p10, v0.w, acc1[3]);       \
    acc1[4]  = fmaf(p11, v1.x, acc1[4]);  acc1[5]  = fmaf(p11, v1.y, acc1[5]);       \
    acc1[6]  = fmaf(p11, v1.z, acc1[6]);  acc1[7]  = fmaf(p11, v1.w, acc1[7]);       \
    acc1[8]  = fmaf(p12, v2.x, acc1[8]);  acc1[9]  = fmaf(p12, v2.y, acc1[9]);       \
    acc1[10] = fmaf(p12, v2.z, acc1[10]); acc1[11] = fmaf(p12, v2.w, acc1[11]);      \
    acc1[12] = fmaf(p13, v3.x, acc1[12]); acc1[13] = fmaf(p13, v3.y, acc1[13]);      \
    acc1[14] = fmaf(p13, v3.z, acc1[14]); acc1[15] = fmaf(p13, v3.w, acc1[15]);      \
} while (0)

__global__ __launch_bounds__(512, 4)
void mlra_kernel(const float* __restrict__ pv,       // [R*K,8]
                 const int*   __restrict__ ele_idx,  // [R*K]
                 const int*   __restrict__ azi_idx,  // [R*K]
                 const float* __restrict__ vp_w,     // [8,8]
                 const float* __restrict__ vp_b,     // [8]
                 const float* __restrict__ ele_emb,  // [37,4]
                 const float* __restrict__ azi_emb,  // [107,4]
                 const float* __restrict__ ipw,      // [2,48,16]
                 const float* __restrict__ ipb,      // [2,48]
                 const float* __restrict__ outw,     // [2,16,16]
                 const float* __restrict__ outb,     // [2,16]
                 const float* __restrict__ lng,      // [16]
                 const float* __restrict__ lnb,      // [16]
                 float* __restrict__ out)            // [R*K,16]
{
    __shared__ float s_k[K_][16];       // 16000 B
    __shared__ float s_v[K_][16];       // 16000 B
    __shared__ float s_x[K_][SX_S];     // 20000 B (padded stride)
    __shared__ float s_w[768];
    __shared__ float s_b[48];
    __shared__ float s_ow[256];
    __shared__ float s_ob[16];
    __shared__ float s_vpw[64];
    __shared__ float s_vpb[8];
    __shared__ float s_ele[148];
    __shared__ float s_azi[428];
    __shared__ float s_lng[16], s_lnb[16];

    const int r = blockIdx.x;
    const int t = threadIdx.x;

    if (t < 64) s_vpw[t] = vp_w[t];
    if (t < 8)  s_vpb[t] = vp_b[t];
    for (int i = t; i < 148; i += 512) s_ele[i] = ele_emb[i];
    for (int i = t; i < 428; i += 512) s_azi[i] = azi_emb[i];
    if (t < 16) { s_lng[t] = lng[t]; s_lnb[t] = lnb[t]; }
    __syncthreads();

    // ---- prologue: threads t<250 build x row t -> s_x ----
    if (t < K_) {
        const size_t row = (size_t)r * K_ + t;
        const float4 p0 = ((const float4*)(pv + row * 8))[0];
        const float4 p1 = ((const float4*)(pv + row * 8))[1];
        const float a[8] = {p0.x,p0.y,p0.z,p0.w,p1.x,p1.y,p1.z,p1.w};
        float xr[16];
        #pragma unroll
        for (int o = 0; o < 8; ++o) {
            const float4 w0 = ((const float4*)&s_vpw[o*8])[0];
            const float4 w1 = ((const float4*)&s_vpw[o*8])[1];
            float s = s_vpb[o];
            s = fmaf(a[0],w0.x,s); s = fmaf(a[1],w0.y,s); s = fmaf(a[2],w0.z,s); s = fmaf(a[3],w0.w,s);
            s = fmaf(a[4],w1.x,s); s = fmaf(a[5],w1.y,s); s = fmaf(a[6],w1.z,s); s = fmaf(a[7],w1.w,s);
            xr[o] = s;
        }
        const int ei = ele_idx[row];
        const int ai = azi_idx[row];
        const float4 ee = *(const float4*)&s_ele[ei*4];
        const float4 ae = *(const float4*)&s_azi[ai*4];
        xr[8]=ee.x; xr[9]=ee.y; xr[10]=ee.z; xr[11]=ee.w;
        xr[12]=ae.x; xr[13]=ae.y; xr[14]=ae.z; xr[15]=ae.w;
        float4* xd = (float4*)&s_x[t][0];
        xd[0] = make_float4(xr[0],xr[1],xr[2],xr[3]);
        xd[1] = make_float4(xr[4],xr[5],xr[6],xr[7]);
        xd[2] = make_float4(xr[8],xr[9],xr[10],xr[11]);
        xd[3] = make_float4(xr[12],xr[13],xr[14],xr[15]);
    }

    // thread = (qpair, quarter): 2 query rows, 1/4 of the keys (strided)
    const int  qp      = t >> 2;        // 0..124 active
    const int  quarter = t & 3;
    const bool act     = qp < 125;
    const int  q0row   = 2*qp;
    const int  q1row   = 2*qp + 1;
    const int  od      = 4*quarter;     // this lane's output-dim chunk

    for (int l = 0; l < L_; ++l) {
        __syncthreads();   // prev-layer epilogue s_x writes / s_ow readers done
        for (int i = t; i < 768; i += 512) s_w[i] = ipw[l*768 + i];
        if (t < 48)  s_b[t]  = ipb[l*48 + t];
        if (t < 256) s_ow[t] = outw[l*256 + t];
        if (t < 16)  s_ob[t] = outb[l*16 + t];
        __syncthreads();

        // ---- QKV: q0,q1 in regs (shared weight loads); one K or V row per thread ----
        float q0[16], q1[16];
        if (act) {
            float x0[16], x1[16];
            {
                const float4* xa = (const float4*)&s_x[q0row][0];
                const float4 a0 = xa[0], a1 = xa[1], a2 = xa[2], a3 = xa[3];
                x0[0]=a0.x; x0[1]=a0.y; x0[2]=a0.z; x0[3]=a0.w;
                x0[4]=a1.x; x0[5]=a1.y; x0[6]=a1.z; x0[7]=a1.w;
                x0[8]=a2.x; x0[9]=a2.y; x0[10]=a2.z; x0[11]=a2.w;
                x0[12]=a3.x; x0[13]=a3.y; x0[14]=a3.z; x0[15]=a3.w;
                const float4* xb = (const float4*)&s_x[q1row][0];
                const float4 b0 = xb[0], b1 = xb[1], b2 = xb[2], b3 = xb[3];
                x1[0]=b0.x; x1[1]=b0.y; x1[2]=b0.z; x1[3]=b0.w;
                x1[4]=b1.x; x1[5]=b1.y; x1[6]=b1.z; x1[7]=b1.w;
                x1[8]=b2.x; x1[9]=b2.y; x1[10]=b2.z; x1[11]=b2.w;
                x1[12]=b3.x; x1[13]=b3.y; x1[14]=b3.z; x1[15]=b3.w;
            }
            #pragma unroll
            for (int o = 0; o < 16; ++o) {
                const float4 w0 = ((const float4*)&s_w[o*16])[0];
                const float4 w1 = ((const float4*)&s_w[o*16])[1];
                const float4 w2 = ((const float4*)&s_w[o*16])[2];
                const float4 w3 = ((const float4*)&s_w[o*16])[3];
                const float b = s_b[o];
                float a0 = b, a1 = b;
                a0=fmaf(x0[0],w0.x,a0); a0=fmaf(x0[1],w0.y,a0); a0=fmaf(x0[2],w0.z,a0); a0=fmaf(x0[3],w0.w,a0);
                a0=fmaf(x0[4],w1.x,a0); a0=fmaf(x0[5],w1.y,a0); a0=fmaf(x0[6],w1.z,a0); a0=fmaf(x0[7],w1.w,a0);
                a0=fmaf(x0[8],w2.x,a0); a0=fmaf(x0[9],w2.y,a0); a0=fmaf(x0[10],w2.z,a0); a0=fmaf(x0[11],w2.w,a0);
                a0=fmaf(x0[12],w3.x,a0); a0=fmaf(x0[13],w3.y,a0); a0=fmaf(x0[14],w3.z,a0); a0=fmaf(x0[15],w3.w,a0);
                a1=fmaf(x1[0],w0.x,a1); a1=fmaf(x1[1],w0.y,a1); a1=fmaf(x1[2],w0.z,a1); a1=fmaf(x1[3],w0.w,a1);
                a1=fmaf(x1[4],w1.x,a1); a1=fmaf(x1[5],w1.y,a1); a1=fmaf(x1[6],w1.z,a1); a1=fmaf(x1[7],w1.w,a1);
                a1=fmaf(x1[8],w2.x,a1); a1=fmaf(x1[9],w2.y,a1); a1=fmaf(x1[10],w2.z,a1); a1=fmaf(x1[11],w2.w,a1);
                a1=fmaf(x1[12],w3.x,a1); a1=fmaf(x1[13],w3.y,a1); a1=fmaf(x1[14],w3.z,a1); a1=fmaf(x1[15],w3.w,a1);
                q0[o] = a0 * SCALE_LOG2E;
                q1[o] = a1 * SCALE_LOG2E;
            }
            // K (quarters 0,1) or V (2,3) row for x row q0row+(quarter&1)
            float xs[16];
            #pragma unroll
            for (int i = 0; i < 16; ++i) xs[i] = (quarter & 1) ? x1[i] : x0[i];
            const int kvb = (quarter < 2) ? 16 : 32;
            float kv[16];
            #pragma unroll
            for (int o = 0; o < 16; ++o) {
                const float* wr = &s_w[(kvb + o)*16];
                const float4 w0 = ((const float4*)wr)[0];
                const float4 w1 = ((const float4*)wr)[1];
                const float4 w2 = ((const float4*)wr)[2];
                const float4 w3 = ((const float4*)wr)[3];
                float s = s_b[kvb + o];
                s=fmaf(xs[0],w0.x,s); s=fmaf(xs[1],w0.y,s); s=fmaf(xs[2],w0.z,s); s=fmaf(xs[3],w0.w,s);
                s=fmaf(xs[4],w1.x,s); s=fmaf(xs[5],w1.y,s); s=fmaf(xs[6],w1.z,s); s=fmaf(xs[7],w1.w,s);
                s=fmaf(xs[8],w2.x,s); s=fmaf(xs[9],w2.y,s); s=fmaf(xs[10],w2.z,s); s=fmaf(xs[11],w2.w,s);
                s=fmaf(xs[12],w3.x,s); s=fmaf(xs[13],w3.y,s); s=fmaf(xs[14],w3.z,s); s=fmaf(xs[15],w3.w,s);
                kv[o] = s;
            }
            float* dst = ((quarter < 2) ? &s_k[0][0] : &s_v[0][0]) + (q0row + (quarter & 1))*16;
            ((float4*)dst)[0] = make_float4(kv[0],kv[1],kv[2],kv[3]);
            ((float4*)dst)[1] = make_float4(kv[4],kv[5],kv[6],kv[7]);
            ((float4*)dst)[2] = make_float4(kv[8],kv[9],kv[10],kv[11]);
            ((float4*)dst)[3] = make_float4(kv[12],kv[13],kv[14],kv[15]);
        }
        __syncthreads();

        // ---- attention: 2 queries x strided quarter of keys; max-free softmax ----
        if (act) {
            float acc0[16], acc1[16];
            #pragma unroll
            for (int i = 0; i < 16; ++i) { acc0[i] = 0.0f; acc1[i] = 0.0f; }
            float ls0=0.f, ls1=0.f, ls2=0.f, ls3=0.f, ls4=0.f, ls5=0.f, ls6=0.f, ls7=0.f;

            const float* kp  = &s_k[quarter][0];
            const float* vp2 = &s_v[quarter][0];
            #pragma unroll 2
            for (int jj = 0; jj < 62; ++jj) {
                ATT_STEP(kp, vp2);
                kp += 64; vp2 += 64;
            }
            if (quarter < 2) {          // rows 248,249
                ATT_STEP(kp, vp2);
            }

            // combine 4 key-quarters (quad-local xor1 then xor2 -> DPP)
            #pragma unroll
            for (int i = 0; i < 16; ++i) {
                acc0[i] += __shfl_xor(acc0[i], 1);
                acc1[i] += __shfl_xor(acc1[i], 1);
            }
            ls0 += __shfl_xor(ls0,1); ls1 += __shfl_xor(ls1,1);
            ls2 += __shfl_xor(ls2,1); ls3 += __shfl_xor(ls3,1);
            ls4 += __shfl_xor(ls4,1); ls5 += __shfl_xor(ls5,1);
            ls6 += __shfl_xor(ls6,1); ls7 += __shfl_xor(ls7,1);
            #pragma unroll
            for (int i = 0; i < 16; ++i) {
                acc0[i] += __shfl_xor(acc0[i], 2);
                acc1[i] += __shfl_xor(acc1[i], 2);
            }
            ls0 += __shfl_xor(ls0,2); ls1 += __shfl_xor(ls1,2);
            ls2 += __shfl_xor(ls2,2); ls3 += __shfl_xor(ls3,2);
            ls4 += __shfl_xor(ls4,2); ls5 += __shfl_xor(ls5,2);
            ls6 += __shfl_xor(ls6,2); ls7 += __shfl_xor(ls7,2);

            // softmax normalize
            const float i00 = __builtin_amdgcn_rcpf(ls0);
            const float i01 = __builtin_amdgcn_rcpf(ls1);
            const float i02 = __builtin_amdgcn_rcpf(ls2);
            const float i03 = __builtin_amdgcn_rcpf(ls3);
            const float i10 = __builtin_amdgcn_rcpf(ls4);
            const float i11 = __builtin_amdgcn_rcpf(ls5);
            const float i12 = __builtin_amdgcn_rcpf(ls6);
            const float i13 = __builtin_amdgcn_rcpf(ls7);
            float o0[16], o1[16];
            o0[0]=acc0[0]*i00;  o0[1]=acc0[1]*i00;  o0[2]=acc0[2]*i00;  o0[3]=acc0[3]*i00;
            o0[4]=acc0[4]*i01;  o0[5]=acc0[5]*i01;  o0[6]=acc0[6]*i01;  o0[7]=acc0[7]*i01;
            o0[8]=acc0[8]*i02;  o0[9]=acc0[9]*i02;  o0[10]=acc0[10]*i02; o0[11]=acc0[11]*i02;
            o0[12]=acc0[12]*i03; o0[13]=acc0[13]*i03; o0[14]=acc0[14]*i03; o0[15]=acc0[15]*i03;
            o1[0]=acc1[0]*i10;  o1[1]=acc1[1]*i10;  o1[2]=acc1[2]*i10;  o1[3]=acc1[3]*i10;
            o1[4]=acc1[4]*i11;  o1[5]=acc1[5]*i11;  o1[6]=acc1[6]*i11;  o1[7]=acc1[7]*i11;
            o1[8]=acc1[8]*i12;  o1[9]=acc1[9]*i12;  o1[10]=acc1[10]*i12; o1[11]=acc1[11]*i12;
            o1[12]=acc1[12]*i13; o1[13]=acc1[13]*i13; o1[14]=acc1[14]*i13; o1[15]=acc1[15]*i13;

            // quad-split epilogue: this lane computes output dims [od, od+4) of both queries
            float y0[4], y1[4];
            #pragma unroll
            for (int c = 0; c < 4; ++c) {
                const float* wr = &s_ow[(od + c)*16];
                const float4 w0 = ((const float4*)wr)[0];
                const float4 w1 = ((const float4*)wr)[1];
                const float4 w2 = ((const float4*)wr)[2];
                const float4 w3 = ((const float4*)wr)[3];
                const float b = s_ob[od + c];
                float a0 = b, a1 = b;
                a0=fmaf(o0[0],w0.x,a0); a0=fmaf(o0[1],w0.y,a0); a0=fmaf(o0[2],w0.z,a0); a0=fmaf(o0[3],w0.w,a0);
                a0=fmaf(o0[4],w1.x,a0); a0=fmaf(o0[5],w1.y,a0); a0=fmaf(o0[6],w1.z,a0); a0=fmaf(o0[7],w1.w,a0);
                a0=fmaf(o0[8],w2.x,a0); a0=fmaf(o0[9],w2.y,a0); a0=fmaf(o0[10],w2.z,a0); a0=fmaf(o0[11],w2.w,a0);
                a0=fmaf(o0[12],w3.x,a0); a0=fmaf(o0[13],w3.y,a0); a0=fmaf(o0[14],w3.z,a0); a0=fmaf(o0[15],w3.w,a0);
                a1=fmaf(o1[0],w0.x,a1); a1=fmaf(o1[1],w0.y,a1); a1=fmaf(o1[2],w0.z,a1); a1=fmaf(o1[3],w0.w,a1);
                a1=fmaf(o1[4],w1.x,a1); a1=fmaf(o1[5],w1.y,a1); a1=fmaf(o1[6],w1.z,a1); a1=fmaf(o1[7],w1.w,a1);
                a1=fmaf(o1[8],w2.x,a1); a1=fmaf(o1[9],w2.y,a1); a1=fmaf(o1[10],w2.z,a1); a1=fmaf(o1[11],w2.w,a1);
                a1=fmaf(o1[12],w3.x,a1); a1=fmaf(o1[13],w3.y,a1); a1=fmaf(o1[14],w3.z,a1); a1=fmaf(o1[15],w3.w,a1);
                y0[c] = a0; y1[c] = a1;
            }
            // residual (read own 4-dim chunk of old x), LN stats via quad reduce
            const float4 xr0 = *(const float4*)&s_x[q0row][od];
            const float4 xr1 = *(const float4*)&s_x[q1row][od];
            const float t00 = y0[0]+xr0.x, t01 = y0[1]+xr0.y, t02 = y0[2]+xr0.z, t03 = y0[3]+xr0.w;
            const float t10 = y1[0]+xr1.x, t11 = y1[1]+xr1.y, t12 = y1[2]+xr1.z, t13 = y1[3]+xr1.w;
            float sum0 = (t00+t01)+(t02+t03);
            float sq0  = fmaf(t00,t00, fmaf(t01,t01, fmaf(t02,t02, t03*t03)));
            float sum1 = (t10+t11)+(t12+t13);
            float sq1  = fmaf(t10,t10, fmaf(t11,t11, fmaf(t12,t12, t13*t13)));
            sum0 += __shfl_xor(sum0,1); sum0 += __shfl_xor(sum0,2);
            sq0  += __shfl_xor(sq0,1);  sq0  += __shfl_xor(sq0,2);
            sum1 += __shfl_xor(sum1,1); sum1 += __shfl_xor(sum1,2);
            sq1  += __shfl_xor(sq1,1);  sq1  += __shfl_xor(sq1,2);
            const float mu0 = sum0 * 0.0625f;
            const float mu1 = sum1 * 0.0625f;
            const float var0 = fmaf(-mu0, mu0, sq0 * 0.0625f);
            const float var1 = fmaf(-mu1, mu1, sq1 * 0.0625f);
            const float rs0 = __builtin_amdgcn_rsqf(var0 + 1e-5f);
            const float rs1 = __builtin_amdgcn_rsqf(var1 + 1e-5f);
            const float4 g  = *(const float4*)&s_lng[od];
            const float4 bb = *(const float4*)&s_lnb[od];
            float4 xn0, xn1;
            xn0.x = (t00-mu0)*rs0*g.x + bb.x;  xn0.y = (t01-mu0)*rs0*g.y + bb.y;
            xn0.z = (t02-mu0)*rs0*g.z + bb.z;  xn0.w = (t03-mu0)*rs0*g.w + bb.w;
            xn1.x = (t10-mu1)*rs1*g.x + bb.x;  xn1.y = (t11-mu1)*rs1*g.y + bb.y;
            xn1.z = (t12-mu1)*rs1*g.z + bb.z;  xn1.w = (t13-mu1)*rs1*g.w + bb.w;
            *(float4*)&s_x[q0row][od] = xn0;   // quad-local: safe within wave
            *(float4*)&s_x[q1row][od] = xn1;
            if (l == L_ - 1) {
                float* ob = out + ((size_t)r*K_ + q0row)*16 + od;
                *(float4*)ob        = xn0;
                *(float4*)(ob + 16) = xn1;
            }
        }
    }
}

extern "C" void kernel_launch(void* const* d_in, const int* in_sizes, int n_in,
                              void* d_out, int out_size, void* d_ws, size_t ws_size,
                              hipStream_t stream) {
    const float* pv      = (const float*)d_in[0];
    const int*   ele_idx = (const int*)  d_in[1];
    const int*   azi_idx = (const int*)  d_in[2];
    const float* vp_w    = (const float*)d_in[3];
    const float* vp_b    = (const float*)d_in[4];
    const float* ele_emb = (const float*)d_in[5];
    const float* azi_emb = (const float*)d_in[6];
    const float* ipw     = (const float*)d_in[7];
    const float* ipb     = (const float*)d_in[8];
    const float* outw    = (const float*)d_in[9];
    const float* outb    = (const float*)d_in[10];
    const float* lng     = (const float*)d_in[11];
    const float* lnb     = (const float*)d_in[12];
    float* out = (float*)d_out;

    mlra_kernel<<<R_, 512, 0, stream>>>(pv, ele_idx, azi_idx, vp_w, vp_b,
                                        ele_emb, azi_emb, ipw, ipb,
                                        outw, outb, lng, lnb, out);
}

// Round 5
// 189.105 us; speedup vs baseline: 1.0549x; 1.0549x over previous
//
#include <hip/hip_runtime.h>

#define R_ 512
#define K_ 250
#define E_ 16
#define L_ 2
#define SX_S 20   // padded s_x row stride (floats) to spread LDS banks

// fold 1/sqrt(D)=0.5 and log2(e) into q so softmax prob = exp2(dot)
#define SCALE_LOG2E 0.72134752044448170f

#define ATT_STEP(KP, VP) do {                                                        \
    const float4 k0 = ((const float4*)(KP))[0];                                      \
    const float4 k1 = ((const float4*)(KP))[1];                                      \
    const float4 k2 = ((const float4*)(KP))[2];                                      \
    const float4 k3 = ((const float4*)(KP))[3];                                      \
    float s00 = fmaf(q0[0],k0.x, fmaf(q0[1],k0.y, fmaf(q0[2],k0.z, q0[3]*k0.w)));    \
    float s01 = fmaf(q0[4],k1.x, fmaf(q0[5],k1.y, fmaf(q0[6],k1.z, q0[7]*k1.w)));    \
    float s02 = fmaf(q0[8],k2.x, fmaf(q0[9],k2.y, fmaf(q0[10],k2.z, q0[11]*k2.w)));  \
    float s03 = fmaf(q0[12],k3.x, fmaf(q0[13],k3.y, fmaf(q0[14],k3.z, q0[15]*k3.w)));\
    float s10 = fmaf(q1[0],k0.x, fmaf(q1[1],k0.y, fmaf(q1[2],k0.z, q1[3]*k0.w)));    \
    float s11 = fmaf(q1[4],k1.x, fmaf(q1[5],k1.y, fmaf(q1[6],k1.z, q1[7]*k1.w)));    \
    float s12 = fmaf(q1[8],k2.x, fmaf(q1[9],k2.y, fmaf(q1[10],k2.z, q1[11]*k2.w)));  \
    float s13 = fmaf(q1[12],k3.x, fmaf(q1[13],k3.y, fmaf(q1[14],k3.z, q1[15]*k3.w)));\
    const float p00 = __builtin_amdgcn_exp2f(s00);                                   \
    const float p01 = __builtin_amdgcn_exp2f(s01);                                   \
    const float p02 = __builtin_amdgcn_exp2f(s02);                                   \
    const float p03 = __builtin_amdgcn_exp2f(s03);                                   \
    const float p10 = __builtin_amdgcn_exp2f(s10);                                   \
    const float p11 = __builtin_amdgcn_exp2f(s11);                                   \
    const float p12 = __builtin_amdgcn_exp2f(s12);                                   \
    const float p13 = __builtin_amdgcn_exp2f(s13);                                   \
    const float4 v0 = ((const float4*)(VP))[0];                                      \
    const float4 v1 = ((const float4*)(VP))[1];                                      \
    const float4 v2 = ((const float4*)(VP))[2];                                      \
    const float4 v3 = ((const float4*)(VP))[3];                                      \
    ls0 += p00; ls1 += p01; ls2 += p02; ls3 += p03;                                  \
    ls4 += p10; ls5 += p11; ls6 += p12; ls7 += p13;                                  \
    acc0[0]  = fmaf(p00, v0.x, acc0[0]);  acc0[1]  = fmaf(p00, v0.y, acc0[1]);       \
    acc0[2]  = fmaf(p00, v0.z, acc0[2]);  acc0[3]  = fmaf(p00, v0.w, acc0[3]);       \
    acc0[4]  = fmaf(p01, v1.x, acc0[4]);  acc0[5]  = fmaf(p01, v1.y, acc0[5]);       \
    acc0[6]  = fmaf(p01, v1.z, acc0[6]);  acc0[7]  = fmaf(p01, v1.w, acc0[7]);       \
    acc0[8]  = fmaf(p02, v2.x, acc0[8]);  acc0[9]  = fmaf(p02, v2.y, acc0[9]);       \
    acc0[10] = fmaf(p02, v2.z, acc0[10]); acc0[11] = fmaf(p02, v2.w, acc0[11]);      \
    acc0[12] = fmaf(p03, v3.x, acc0[12]); acc0[13] = fmaf(p03, v3.y, acc0[13]);      \
    acc0[14] = fmaf(p03, v3.z, acc0[14]); acc0[15] = fmaf(p03, v3.w, acc0[15]);      \
    acc1[0]  = fmaf(p10, v0.x, acc1[0]);  acc1[1]  = fmaf(p10, v0.y, acc1[1]);       \
    acc1[2]  = fmaf(p10, v0.z, acc1[2]);  acc1[3]  = fmaf(p10, v0.w, acc1[3]);       \
    acc1[4]  = fmaf(p11, v1.x, acc1[4]);  acc1[5]  = fmaf(p11, v1.y, acc1[5]);       \
    acc1[6]  = fmaf(p11, v1.z, acc1[6]);  acc1[7]  = fmaf(p11, v1.w, acc1[7]);       \
    acc1[8]  = fmaf(p12, v2.x, acc1[8]);  acc1[9]  = fmaf(p12, v2.y, acc1[9]);       \
    acc1[10] = fmaf(p12, v2.z, acc1[10]); acc1[11] = fmaf(p12, v2.w, acc1[11]);      \
    acc1[12] = fmaf(p13, v3.x, acc1[12]); acc1[13] = fmaf(p13, v3.y, acc1[13]);      \
    acc1[14] = fmaf(p13, v3.z, acc1[14]); acc1[15] = fmaf(p13, v3.w, acc1[15]);      \
} while (0)

__global__ __launch_bounds__(512, 2)   // was (512,4): 64-VGPR cap caused ~140MB scratch spill
void mlra_kernel(const float* __restrict__ pv,       // [R*K,8]
                 const int*   __restrict__ ele_idx,  // [R*K]
                 const int*   __restrict__ azi_idx,  // [R*K]
                 const float* __restrict__ vp_w,     // [8,8]
                 const float* __restrict__ vp_b,     // [8]
                 const float* __restrict__ ele_emb,  // [37,4]
                 const float* __restrict__ azi_emb,  // [107,4]
                 const float* __restrict__ ipw,      // [2,48,16]
                 const float* __restrict__ ipb,      // [2,48]
                 const float* __restrict__ outw,     // [2,16,16]
                 const float* __restrict__ outb,     // [2,16]
                 const float* __restrict__ lng,      // [16]
                 const float* __restrict__ lnb,      // [16]
                 float* __restrict__ out)            // [R*K,16]
{
    __shared__ float s_k[K_][16];       // 16000 B
    __shared__ float s_v[K_][16];       // 16000 B
    __shared__ float s_x[K_][SX_S];     // 20000 B (padded stride)
    __shared__ float s_w[768];
    __shared__ float s_b[48];
    __shared__ float s_ow[256];
    __shared__ float s_ob[16];
    __shared__ float s_vpw[64];
    __shared__ float s_vpb[8];
    __shared__ float s_ele[148];
    __shared__ float s_azi[428];
    __shared__ float s_lng[16], s_lnb[16];

    const int r = blockIdx.x;
    const int t = threadIdx.x;

    if (t < 64) s_vpw[t] = vp_w[t];
    if (t < 8)  s_vpb[t] = vp_b[t];
    for (int i = t; i < 148; i += 512) s_ele[i] = ele_emb[i];
    for (int i = t; i < 428; i += 512) s_azi[i] = azi_emb[i];
    if (t < 16) { s_lng[t] = lng[t]; s_lnb[t] = lnb[t]; }
    __syncthreads();

    // ---- prologue: threads t<250 build x row t -> s_x ----
    if (t < K_) {
        const size_t row = (size_t)r * K_ + t;
        const float4 p0 = ((const float4*)(pv + row * 8))[0];
        const float4 p1 = ((const float4*)(pv + row * 8))[1];
        const float a[8] = {p0.x,p0.y,p0.z,p0.w,p1.x,p1.y,p1.z,p1.w};
        float xr[16];
        #pragma unroll
        for (int o = 0; o < 8; ++o) {
            const float4 w0 = ((const float4*)&s_vpw[o*8])[0];
            const float4 w1 = ((const float4*)&s_vpw[o*8])[1];
            float s = s_vpb[o];
            s = fmaf(a[0],w0.x,s); s = fmaf(a[1],w0.y,s); s = fmaf(a[2],w0.z,s); s = fmaf(a[3],w0.w,s);
            s = fmaf(a[4],w1.x,s); s = fmaf(a[5],w1.y,s); s = fmaf(a[6],w1.z,s); s = fmaf(a[7],w1.w,s);
            xr[o] = s;
        }
        const int ei = ele_idx[row];
        const int ai = azi_idx[row];
        const float4 ee = *(const float4*)&s_ele[ei*4];
        const float4 ae = *(const float4*)&s_azi[ai*4];
        xr[8]=ee.x; xr[9]=ee.y; xr[10]=ee.z; xr[11]=ee.w;
        xr[12]=ae.x; xr[13]=ae.y; xr[14]=ae.z; xr[15]=ae.w;
        float4* xd = (float4*)&s_x[t][0];
        xd[0] = make_float4(xr[0],xr[1],xr[2],xr[3]);
        xd[1] = make_float4(xr[4],xr[5],xr[6],xr[7]);
        xd[2] = make_float4(xr[8],xr[9],xr[10],xr[11]);
        xd[3] = make_float4(xr[12],xr[13],xr[14],xr[15]);
    }

    // thread = (qpair, quarter): 2 query rows, 1/4 of the keys (strided)
    const int  qp      = t >> 2;        // 0..124 active
    const int  quarter = t & 3;
    const bool act     = qp < 125;
    const int  q0row   = 2*qp;
    const int  q1row   = 2*qp + 1;
    const int  od      = 4*quarter;     // this lane's output-dim chunk

    for (int l = 0; l < L_; ++l) {
        __syncthreads();   // prev-layer epilogue s_x writes / s_ow readers done
        for (int i = t; i < 768; i += 512) s_w[i] = ipw[l*768 + i];
        if (t < 48)  s_b[t]  = ipb[l*48 + t];
        if (t < 256) s_ow[t] = outw[l*256 + t];
        if (t < 16)  s_ob[t] = outb[l*16 + t];
        __syncthreads();

        // ---- QKV: q0,q1 in regs (shared weight loads); one K or V row per thread ----
        float q0[16], q1[16];
        if (act) {
            float x0[16], x1[16];
            {
                const float4* xa = (const float4*)&s_x[q0row][0];
                const float4 a0 = xa[0], a1 = xa[1], a2 = xa[2], a3 = xa[3];
                x0[0]=a0.x; x0[1]=a0.y; x0[2]=a0.z; x0[3]=a0.w;
                x0[4]=a1.x; x0[5]=a1.y; x0[6]=a1.z; x0[7]=a1.w;
                x0[8]=a2.x; x0[9]=a2.y; x0[10]=a2.z; x0[11]=a2.w;
                x0[12]=a3.x; x0[13]=a3.y; x0[14]=a3.z; x0[15]=a3.w;
                const float4* xb = (const float4*)&s_x[q1row][0];
                const float4 b0 = xb[0], b1 = xb[1], b2 = xb[2], b3 = xb[3];
                x1[0]=b0.x; x1[1]=b0.y; x1[2]=b0.z; x1[3]=b0.w;
                x1[4]=b1.x; x1[5]=b1.y; x1[6]=b1.z; x1[7]=b1.w;
                x1[8]=b2.x; x1[9]=b2.y; x1[10]=b2.z; x1[11]=b2.w;
                x1[12]=b3.x; x1[13]=b3.y; x1[14]=b3.z; x1[15]=b3.w;
            }
            #pragma unroll
            for (int o = 0; o < 16; ++o) {
                const float4 w0 = ((const float4*)&s_w[o*16])[0];
                const float4 w1 = ((const float4*)&s_w[o*16])[1];
                const float4 w2 = ((const float4*)&s_w[o*16])[2];
                const float4 w3 = ((const float4*)&s_w[o*16])[3];
                const float b = s_b[o];
                float a0 = b, a1 = b;
                a0=fmaf(x0[0],w0.x,a0); a0=fmaf(x0[1],w0.y,a0); a0=fmaf(x0[2],w0.z,a0); a0=fmaf(x0[3],w0.w,a0);
                a0=fmaf(x0[4],w1.x,a0); a0=fmaf(x0[5],w1.y,a0); a0=fmaf(x0[6],w1.z,a0); a0=fmaf(x0[7],w1.w,a0);
                a0=fmaf(x0[8],w2.x,a0); a0=fmaf(x0[9],w2.y,a0); a0=fmaf(x0[10],w2.z,a0); a0=fmaf(x0[11],w2.w,a0);
                a0=fmaf(x0[12],w3.x,a0); a0=fmaf(x0[13],w3.y,a0); a0=fmaf(x0[14],w3.z,a0); a0=fmaf(x0[15],w3.w,a0);
                a1=fmaf(x1[0],w0.x,a1); a1=fmaf(x1[1],w0.y,a1); a1=fmaf(x1[2],w0.z,a1); a1=fmaf(x1[3],w0.w,a1);
                a1=fmaf(x1[4],w1.x,a1); a1=fmaf(x1[5],w1.y,a1); a1=fmaf(x1[6],w1.z,a1); a1=fmaf(x1[7],w1.w,a1);
                a1=fmaf(x1[8],w2.x,a1); a1=fmaf(x1[9],w2.y,a1); a1=fmaf(x1[10],w2.z,a1); a1=fmaf(x1[11],w2.w,a1);
                a1=fmaf(x1[12],w3.x,a1); a1=fmaf(x1[13],w3.y,a1); a1=fmaf(x1[14],w3.z,a1); a1=fmaf(x1[15],w3.w,a1);
                q0[o] = a0 * SCALE_LOG2E;
                q1[o] = a1 * SCALE_LOG2E;
            }
            // K (quarters 0,1) or V (2,3) row for x row q0row+(quarter&1)
            float xs[16];
            #pragma unroll
            for (int i = 0; i < 16; ++i) xs[i] = (quarter & 1) ? x1[i] : x0[i];
            const int kvb = (quarter < 2) ? 16 : 32;
            float kv[16];
            #pragma unroll
            for (int o = 0; o < 16; ++o) {
                const float* wr = &s_w[(kvb + o)*16];
                const float4 w0 = ((const float4*)wr)[0];
                const float4 w1 = ((const float4*)wr)[1];
                const float4 w2 = ((const float4*)wr)[2];
                const float4 w3 = ((const float4*)wr)[3];
                float s = s_b[kvb + o];
                s=fmaf(xs[0],w0.x,s); s=fmaf(xs[1],w0.y,s); s=fmaf(xs[2],w0.z,s); s=fmaf(xs[3],w0.w,s);
                s=fmaf(xs[4],w1.x,s); s=fmaf(xs[5],w1.y,s); s=fmaf(xs[6],w1.z,s); s=fmaf(xs[7],w1.w,s);
                s=fmaf(xs[8],w2.x,s); s=fmaf(xs[9],w2.y,s); s=fmaf(xs[10],w2.z,s); s=fmaf(xs[11],w2.w,s);
                s=fmaf(xs[12],w3.x,s); s=fmaf(xs[13],w3.y,s); s=fmaf(xs[14],w3.z,s); s=fmaf(xs[15],w3.w,s);
                kv[o] = s;
            }
            float* dst = ((quarter < 2) ? &s_k[0][0] : &s_v[0][0]) + (q0row + (quarter & 1))*16;
            ((float4*)dst)[0] = make_float4(kv[0],kv[1],kv[2],kv[3]);
            ((float4*)dst)[1] = make_float4(kv[4],kv[5],kv[6],kv[7]);
            ((float4*)dst)[2] = make_float4(kv[8],kv[9],kv[10],kv[11]);
            ((float4*)dst)[3] = make_float4(kv[12],kv[13],kv[14],kv[15]);
        }
        __syncthreads();

        // ---- attention: 2 queries x strided quarter of keys; max-free softmax ----
        if (act) {
            float acc0[16], acc1[16];
            #pragma unroll
            for (int i = 0; i < 16; ++i) { acc0[i] = 0.0f; acc1[i] = 0.0f; }
            float ls0=0.f, ls1=0.f, ls2=0.f, ls3=0.f, ls4=0.f, ls5=0.f, ls6=0.f, ls7=0.f;

            const float* kp  = &s_k[quarter][0];
            const float* vp2 = &s_v[quarter][0];
            #pragma unroll 2
            for (int jj = 0; jj < 62; ++jj) {
                ATT_STEP(kp, vp2);
                kp += 64; vp2 += 64;
            }
            if (quarter < 2) {          // rows 248,249
                ATT_STEP(kp, vp2);
            }

            // combine 4 key-quarters (quad-local xor1 then xor2 -> DPP)
            #pragma unroll
            for (int i = 0; i < 16; ++i) {
                acc0[i] += __shfl_xor(acc0[i], 1);
                acc1[i] += __shfl_xor(acc1[i], 1);
            }
            ls0 += __shfl_xor(ls0,1); ls1 += __shfl_xor(ls1,1);
            ls2 += __shfl_xor(ls2,1); ls3 += __shfl_xor(ls3,1);
            ls4 += __shfl_xor(ls4,1); ls5 += __shfl_xor(ls5,1);
            ls6 += __shfl_xor(ls6,1); ls7 += __shfl_xor(ls7,1);
            #pragma unroll
            for (int i = 0; i < 16; ++i) {
                acc0[i] += __shfl_xor(acc0[i], 2);
                acc1[i] += __shfl_xor(acc1[i], 2);
            }
            ls0 += __shfl_xor(ls0,2); ls1 += __shfl_xor(ls1,2);
            ls2 += __shfl_xor(ls2,2); ls3 += __shfl_xor(ls3,2);
            ls4 += __shfl_xor(ls4,2); ls5 += __shfl_xor(ls5,2);
            ls6 += __shfl_xor(ls6,2); ls7 += __shfl_xor(ls7,2);

            // softmax normalize
            const float i00 = __builtin_amdgcn_rcpf(ls0);
            const float i01 = __builtin_amdgcn_rcpf(ls1);
            const float i02 = __builtin_amdgcn_rcpf(ls2);
            const float i03 = __builtin_amdgcn_rcpf(ls3);
            const float i10 = __builtin_amdgcn_rcpf(ls4);
            const float i11 = __builtin_amdgcn_rcpf(ls5);
            const float i12 = __builtin_amdgcn_rcpf(ls6);
            const float i13 = __builtin_amdgcn_rcpf(ls7);
            float o0[16], o1[16];
            o0[0]=acc0[0]*i00;  o0[1]=acc0[1]*i00;  o0[2]=acc0[2]*i00;  o0[3]=acc0[3]*i00;
            o0[4]=acc0[4]*i01;  o0[5]=acc0[5]*i01;  o0[6]=acc0[6]*i01;  o0[7]=acc0[7]*i01;
            o0[8]=acc0[8]*i02;  o0[9]=acc0[9]*i02;  o0[10]=acc0[10]*i02; o0[11]=acc0[11]*i02;
            o0[12]=acc0[12]*i03; o0[13]=acc0[13]*i03; o0[14]=acc0[14]*i03; o0[15]=acc0[15]*i03;
            o1[0]=acc1[0]*i10;  o1[1]=acc1[1]*i10;  o1[2]=acc1[2]*i10;  o1[3]=acc1[3]*i10;
            o1[4]=acc1[4]*i11;  o1[5]=acc1[5]*i11;  o1[6]=acc1[6]*i11;  o1[7]=acc1[7]*i11;
            o1[8]=acc1[8]*i12;  o1[9]=acc1[9]*i12;  o1[10]=acc1[10]*i12; o1[11]=acc1[11]*i12;
            o1[12]=acc1[12]*i13; o1[13]=acc1[13]*i13; o1[14]=acc1[14]*i13; o1[15]=acc1[15]*i13;

            // quad-split epilogue: this lane computes output dims [od, od+4) of both queries
            float y0[4], y1[4];
            #pragma unroll
            for (int c = 0; c < 4; ++c) {
                const float* wr = &s_ow[(od + c)*16];
                const float4 w0 = ((const float4*)wr)[0];
                const float4 w1 = ((const float4*)wr)[1];
                const float4 w2 = ((const float4*)wr)[2];
                const float4 w3 = ((const float4*)wr)[3];
                const float b = s_ob[od + c];
                float a0 = b, a1 = b;
                a0=fmaf(o0[0],w0.x,a0); a0=fmaf(o0[1],w0.y,a0); a0=fmaf(o0[2],w0.z,a0); a0=fmaf(o0[3],w0.w,a0);
                a0=fmaf(o0[4],w1.x,a0); a0=fmaf(o0[5],w1.y,a0); a0=fmaf(o0[6],w1.z,a0); a0=fmaf(o0[7],w1.w,a0);
                a0=fmaf(o0[8],w2.x,a0); a0=fmaf(o0[9],w2.y,a0); a0=fmaf(o0[10],w2.z,a0); a0=fmaf(o0[11],w2.w,a0);
                a0=fmaf(o0[12],w3.x,a0); a0=fmaf(o0[13],w3.y,a0); a0=fmaf(o0[14],w3.z,a0); a0=fmaf(o0[15],w3.w,a0);
                a1=fmaf(o1[0],w0.x,a1); a1=fmaf(o1[1],w0.y,a1); a1=fmaf(o1[2],w0.z,a1); a1=fmaf(o1[3],w0.w,a1);
                a1=fmaf(o1[4],w1.x,a1); a1=fmaf(o1[5],w1.y,a1); a1=fmaf(o1[6],w1.z,a1); a1=fmaf(o1[7],w1.w,a1);
                a1=fmaf(o1[8],w2.x,a1); a1=fmaf(o1[9],w2.y,a1); a1=fmaf(o1[10],w2.z,a1); a1=fmaf(o1[11],w2.w,a1);
                a1=fmaf(o1[12],w3.x,a1); a1=fmaf(o1[13],w3.y,a1); a1=fmaf(o1[14],w3.z,a1); a1=fmaf(o1[15],w3.w,a1);
                y0[c] = a0; y1[c] = a1;
            }
            // residual (read own 4-dim chunk of old x), LN stats via quad reduce
            const float4 xr0 = *(const float4*)&s_x[q0row][od];
            const float4 xr1 = *(const float4*)&s_x[q1row][od];
            const float t00 = y0[0]+xr0.x, t01 = y0[1]+xr0.y, t02 = y0[2]+xr0.z, t03 = y0[3]+xr0.w;
            const float t10 = y1[0]+xr1.x, t11 = y1[1]+xr1.y, t12 = y1[2]+xr1.z, t13 = y1[3]+xr1.w;
            float sum0 = (t00+t01)+(t02+t03);
            float sq0  = fmaf(t00,t00, fmaf(t01,t01, fmaf(t02,t02, t03*t03)));
            float sum1 = (t10+t11)+(t12+t13);
            float sq1  = fmaf(t10,t10, fmaf(t11,t11, fmaf(t12,t12, t13*t13)));
            sum0 += __shfl_xor(sum0,1); sum0 += __shfl_xor(sum0,2);
            sq0  += __shfl_xor(sq0,1);  sq0  += __shfl_xor(sq0,2);
            sum1 += __shfl_xor(sum1,1); sum1 += __shfl_xor(sum1,2);
            sq1  += __shfl_xor(sq1,1);  sq1  += __shfl_xor(sq1,2);
            const float mu0 = sum0 * 0.0625f;
            const float mu1 = sum1 * 0.0625f;
            const float var0 = fmaf(-mu0, mu0, sq0 * 0.0625f);
            const float var1 = fmaf(-mu1, mu1, sq1 * 0.0625f);
            const float rs0 = __builtin_amdgcn_rsqf(var0 + 1e-5f);
            const float rs1 = __builtin_amdgcn_rsqf(var1 + 1e-5f);
            const float4 g  = *(const float4*)&s_lng[od];
            const float4 bb = *(const float4*)&s_lnb[od];
            float4 xn0, xn1;
            xn0.x = (t00-mu0)*rs0*g.x + bb.x;  xn0.y = (t01-mu0)*rs0*g.y + bb.y;
            xn0.z = (t02-mu0)*rs0*g.z + bb.z;  xn0.w = (t03-mu0)*rs0*g.w + bb.w;
            xn1.x = (t10-mu1)*rs1*g.x + bb.x;  xn1.y = (t11-mu1)*rs1*g.y + bb.y;
            xn1.z = (t12-mu1)*rs1*g.z + bb.z;  xn1.w = (t13-mu1)*rs1*g.w + bb.w;
            *(float4*)&s_x[q0row][od] = xn0;   // quad-local: safe within wave
            *(float4*)&s_x[q1row][od] = xn1;
            if (l == L_ - 1) {
                float* ob = out + ((size_t)r*K_ + q0row)*16 + od;
                *(float4*)ob        = xn0;
                *(float4*)(ob + 16) = xn1;
            }
        }
    }
}

extern "C" void kernel_launch(void* const* d_in, const int* in_sizes, int n_in,
                              void* d_out, int out_size, void* d_ws, size_t ws_size,
                              hipStream_t stream) {
    const float* pv      = (const float*)d_in[0];
    const int*   ele_idx = (const int*)  d_in[1];
    const int*   azi_idx = (const int*)  d_in[2];
    const float* vp_w    = (const float*)d_in[3];
    const float* vp_b    = (const float*)d_in[4];
    const float* ele_emb = (const float*)d_in[5];
    const float* azi_emb = (const float*)d_in[6];
    const float* ipw     = (const float*)d_in[7];
    const float* ipb     = (const float*)d_in[8];
    const float* outw    = (const float*)d_in[9];
    const float* outb    = (const float*)d_in[10];
    const float* lng     = (const float*)d_in[11];
    const float* lnb     = (const float*)d_in[12];
    float* out = (float*)d_out;

    mlra_kernel<<<R_, 512, 0, stream>>>(pv, ele_idx, azi_idx, vp_w, vp_b,
                                        ele_emb, azi_emb, ipw, ipb,
                                        outw, outb, lng, lnb, out);
}